// Round 7
// baseline (857.733 us; speedup 1.0000x reference)
//
#include <hip/hip_runtime.h>
#include <stdint.h>

// Problem constants
#define S_DIM 2048
#define B_DIM 4
#define D_DIM 1024
#define E_DIM 8
#define C_DIM 2048
#define FF_DIM 4096
#define N_DIM (S_DIM * B_DIM)  // 8192 tokens

typedef unsigned short u16;
using bf16x8 = __attribute__((ext_vector_type(8))) __bf16;
using u16x8  = __attribute__((ext_vector_type(8))) unsigned short;
using f32x4  = __attribute__((ext_vector_type(4))) float;

// ---------- helpers ----------
__device__ __forceinline__ u16 f2bf(float f) {       // RNE fp32 -> bf16 bits
  uint32_t u = __float_as_uint(f);
  u += 0x7fffu + ((u >> 16) & 1u);
  return (u16)(u >> 16);
}
__device__ __forceinline__ float gelu_tanh(float x) {  // jax.nn.gelu approximate=True
  float u = 0.7978845608028654f * (x + 0.044715f * x * x * x);
  return 0.5f * x * (1.0f + tanhf(u));
}
// async global->LDS, 16B per lane. LDS dest = wave-uniform base + lane*16.
__device__ __forceinline__ void cp16(const void* g, void* l) {
  __builtin_amdgcn_global_load_lds(
      (const __attribute__((address_space(1))) void*)g,
      (__attribute__((address_space(3))) void*)l,
      16, 0, 0);
}

// ---------- dtype detector (validated r3) ----------
__global__ __launch_bounds__(256) void detect_i64_kernel(
    const int* __restrict__ t, int* __restrict__ flag) {
  int i = blockIdx.x * 256 + threadIdx.x;
  if (i < (E_DIM * C_DIM) / 2 && t[2 * i + 1] != 0) atomicOr(flag, 1);
}

// ---------- prep kernels (validated r3) ----------
__global__ __launch_bounds__(256) void prep_tok_kernel(
    const void* __restrict__ top_idx, const float* __restrict__ cw,
    const int* __restrict__ flag, int* __restrict__ tok32, float* __restrict__ wg) {
  int t = blockIdx.x * 256 + threadIdx.x;
  if (t >= E_DIM * C_DIM) return;
  int e = t / C_DIM, c = t % C_DIM;
  int tid;
  if (*flag == 0) {
    tid = (int)((const long long*)top_idx)[(size_t)c * E_DIM + e];
  } else {
    tid = ((const int*)top_idx)[(size_t)c * E_DIM + e];
  }
  tid &= (N_DIM - 1);
  tok32[t] = tid;
  wg[t] = cw[(size_t)tid * E_DIM + e];
}

// split x [N][D] fp32 -> bf16
__global__ __launch_bounds__(256) void split_x_kernel(
    const float* __restrict__ x, u16* __restrict__ xh) {
  size_t i = ((size_t)blockIdx.x * 256 + threadIdx.x) * 8;
  const float4* p = (const float4*)(x + i);
  float4 v0 = p[0], v1 = p[1];
  float vv[8] = {v0.x, v0.y, v0.z, v0.w, v1.x, v1.y, v1.z, v1.w};
  u16x8 hv;
#pragma unroll
  for (int j = 0; j < 8; ++j) hv[j] = f2bf(vv[j]);
  *(u16x8*)(xh + i) = hv;
}

// per-expert transpose: in [E][R][Cc] fp32 -> out [E][Cc][R] bf16 (u16x8 stores)
__global__ __launch_bounds__(256) void trans_split_kernel(
    const float* __restrict__ in, u16* __restrict__ ohi, int R, int Cc) {
  __shared__ float T[64][65];
  const int e = blockIdx.z;
  const int c0 = blockIdx.x * 64, r0 = blockIdx.y * 64;
  const int tx = threadIdx.x & 63, ty = threadIdx.x >> 6;
  const float* ein = in + (size_t)e * R * Cc;
  u16* eh = ohi + (size_t)e * R * Cc;
#pragma unroll
  for (int i = 0; i < 16; ++i) {
    int r = ty + i * 4;
    T[r][tx] = ein[(size_t)(r0 + r) * Cc + (c0 + tx)];
  }
  __syncthreads();
  const int tr = (threadIdx.x & 7) * 8;
  const int cbase = threadIdx.x >> 3;
#pragma unroll
  for (int i = 0; i < 2; ++i) {
    const int c = cbase + i * 32;
    u16x8 hv;
#pragma unroll
    for (int j = 0; j < 8; ++j) hv[j] = f2bf(T[tr + j][c]);
    *(u16x8*)(eh + (size_t)(c0 + c) * R + (r0 + tr)) = hv;
  }
}

// ---------- GEMM1: h[e][c][f] = gelu(x[tok[e,c]] . W1t[e][f] + b1[e][f]) ----------
// 128x128 tile, BK=32, 4 waves, 16x16x32 bf16. Double-buffered LDS with
// issue-early staging (T3 2-phase minimum) + bijective XCD swizzle (T1/m204):
// logical order fb-fastest, expert-major; each XCD gets one expert's chunk.
__global__ __launch_bounds__(256) void gemm1_kernel(
    const u16* __restrict__ xs, const u16* __restrict__ w1t,
    const int* __restrict__ tok32, const float* __restrict__ b1,
    u16* __restrict__ h) {
  __shared__ u16 As[2][4096], Bs[2][4096];
  __shared__ int tok_s[128];

  const int GX = FF_DIM / 128, GY = C_DIM / 128;       // 32, 16
  const int nblk = GX * GY * E_DIM;                    // 4096 (nblk%8==0)
  const int lin = ((int)blockIdx.x & 7) * (nblk / 8) + ((int)blockIdx.x >> 3);
  const int fb = lin % GX;
  const int cb = (lin / GX) % GY;
  const int e  = lin / (GX * GY);

  const int t = threadIdx.x, lane = t & 63, w = t >> 6;
  const int wm = w >> 1, wn = w & 1;

  if (t < 128) tok_s[t] = tok32[e * C_DIM + cb * 128 + t];
  __syncthreads();

  // per-thread global staging pointers (gather fused into A staging)
  const u16 *sA[2], *sB[2];
#pragma unroll
  for (int i = 0; i < 2; ++i) {
    const int q = i * 256 + t, row = q >> 2, sub = q & 3;
    sA[i] = xs + (size_t)tok_s[row] * D_DIM + sub * 8;
    sB[i] = w1t + ((size_t)(e * FF_DIM + fb * 128 + row)) * D_DIM + sub * 8;
  }

  int aOff[4], bOff[4];
#pragma unroll
  for (int mi = 0; mi < 4; ++mi)
    aOff[mi] = (wm * 64 + mi * 16 + (lane & 15)) * 32 + (lane >> 4) * 8;
#pragma unroll
  for (int ni = 0; ni < 4; ++ni)
    bOff[ni] = (wn * 64 + ni * 16 + (lane & 15)) * 32 + (lane >> 4) * 8;

  f32x4 zero = {0.f, 0.f, 0.f, 0.f};
  f32x4 acc[4][4];
#pragma unroll
  for (int mi = 0; mi < 4; ++mi)
#pragma unroll
    for (int ni = 0; ni < 4; ++ni) acc[mi][ni] = zero;

  const int wbase = w * 64 * 8;  // wave-uniform LDS element base

  // prologue: stage tile 0 into buf 0
#pragma unroll
  for (int i = 0; i < 2; ++i) {
    cp16(sA[i], &As[0][i * 2048 + wbase]);
    cp16(sB[i], &Bs[0][i * 2048 + wbase]);
  }
  __syncthreads();

  const int NT = D_DIM / 32;
  for (int kk = 0; kk < NT; ++kk) {
    const int cur = kk & 1;
    if (kk + 1 < NT) {            // issue next-tile loads BEFORE compute (overlap)
      const int ke = (kk + 1) * 32, nxt = cur ^ 1;
#pragma unroll
      for (int i = 0; i < 2; ++i) {
        cp16(sA[i] + ke, &As[nxt][i * 2048 + wbase]);
        cp16(sB[i] + ke, &Bs[nxt][i * 2048 + wbase]);
      }
    }
    bf16x8 af[4], bf[4];
#pragma unroll
    for (int mi = 0; mi < 4; ++mi) af[mi] = *(const bf16x8*)&As[cur][aOff[mi]];
#pragma unroll
    for (int ni = 0; ni < 4; ++ni) bf[ni] = *(const bf16x8*)&Bs[cur][bOff[ni]];
#pragma unroll
    for (int mi = 0; mi < 4; ++mi)
#pragma unroll
      for (int ni = 0; ni < 4; ++ni)
        acc[mi][ni] = __builtin_amdgcn_mfma_f32_16x16x32_bf16(af[mi], bf[ni], acc[mi][ni], 0, 0, 0);
    __syncthreads();  // drains vmcnt (next tile landed) + lgkm, then barrier
  }

  // epilogue: bias + gelu, store h as bf16
  const int c_base0 = cb * 128 + wm * 64;
  const int f_base0 = fb * 128 + wn * 64;
#pragma unroll
  for (int ni = 0; ni < 4; ++ni) {
    const int f = f_base0 + ni * 16 + (lane & 15);
    const float bias = b1[e * FF_DIM + f];
#pragma unroll
    for (int mi = 0; mi < 4; ++mi) {
#pragma unroll
      for (int j = 0; j < 4; ++j) {
        const int c = c_base0 + mi * 16 + (lane >> 4) * 4 + j;
        h[((size_t)(e * C_DIM + c)) * FF_DIM + f] = f2bf(gelu_tanh(acc[mi][ni][j] + bias));
      }
    }
  }
}

// ---------- GEMM2: out[tok] += wg * (h[e][c] . W2t[e][d] + b2[e][d]) ----------
__global__ __launch_bounds__(256) void gemm2_kernel(
    const u16* __restrict__ h, const u16* __restrict__ w2t,
    const int* __restrict__ tok32, const float* __restrict__ wg,
    const float* __restrict__ b2, float* __restrict__ out) {
  __shared__ u16 As[2][4096], Bs[2][4096];
  __shared__ int tok_s[128];
  __shared__ float w_s[128];

  const int GX = D_DIM / 128, GY = C_DIM / 128;        // 8, 16
  const int nblk = GX * GY * E_DIM;                    // 1024 (nblk%8==0)
  const int lin = ((int)blockIdx.x & 7) * (nblk / 8) + ((int)blockIdx.x >> 3);
  const int db = lin % GX;
  const int cb = (lin / GX) % GY;
  const int e  = lin / (GX * GY);

  const int t = threadIdx.x, lane = t & 63, w = t >> 6;
  const int wm = w >> 1, wn = w & 1;

  if (t < 128) {
    tok_s[t] = tok32[e * C_DIM + cb * 128 + t];
    w_s[t] = wg[e * C_DIM + cb * 128 + t];
  }
  // tok_s/w_s only read in epilogue (after the k-loop's barriers)

  const u16 *sA[2], *sB[2];
#pragma unroll
  for (int i = 0; i < 2; ++i) {
    const int q = i * 256 + t, row = q >> 2, sub = q & 3;
    sA[i] = h + ((size_t)(e * C_DIM + cb * 128 + row)) * FF_DIM + sub * 8;
    sB[i] = w2t + ((size_t)(e * D_DIM + db * 128 + row)) * FF_DIM + sub * 8;
  }

  int aOff[4], bOff[4];
#pragma unroll
  for (int mi = 0; mi < 4; ++mi)
    aOff[mi] = (wm * 64 + mi * 16 + (lane & 15)) * 32 + (lane >> 4) * 8;
#pragma unroll
  for (int ni = 0; ni < 4; ++ni)
    bOff[ni] = (wn * 64 + ni * 16 + (lane & 15)) * 32 + (lane >> 4) * 8;

  f32x4 zero = {0.f, 0.f, 0.f, 0.f};
  f32x4 acc[4][4];
#pragma unroll
  for (int mi = 0; mi < 4; ++mi)
#pragma unroll
    for (int ni = 0; ni < 4; ++ni) acc[mi][ni] = zero;

  const int wbase = w * 64 * 8;

  __syncthreads();  // tok_s/w_s visible; also orders LDS reuse
#pragma unroll
  for (int i = 0; i < 2; ++i) {
    cp16(sA[i], &As[0][i * 2048 + wbase]);
    cp16(sB[i], &Bs[0][i * 2048 + wbase]);
  }
  __syncthreads();

  const int NT = FF_DIM / 32;
  for (int kk = 0; kk < NT; ++kk) {
    const int cur = kk & 1;
    if (kk + 1 < NT) {
      const int ke = (kk + 1) * 32, nxt = cur ^ 1;
#pragma unroll
      for (int i = 0; i < 2; ++i) {
        cp16(sA[i] + ke, &As[nxt][i * 2048 + wbase]);
        cp16(sB[i] + ke, &Bs[nxt][i * 2048 + wbase]);
      }
    }
    bf16x8 af[4], bf[4];
#pragma unroll
    for (int mi = 0; mi < 4; ++mi) af[mi] = *(const bf16x8*)&As[cur][aOff[mi]];
#pragma unroll
    for (int ni = 0; ni < 4; ++ni) bf[ni] = *(const bf16x8*)&Bs[cur][bOff[ni]];
#pragma unroll
    for (int mi = 0; mi < 4; ++mi)
#pragma unroll
      for (int ni = 0; ni < 4; ++ni)
        acc[mi][ni] = __builtin_amdgcn_mfma_f32_16x16x32_bf16(af[mi], bf[ni], acc[mi][ni], 0, 0, 0);
    __syncthreads();
  }

  // epilogue: bias, gate weight, scatter-add combine
  const int dbase = db * 128 + wn * 64;
#pragma unroll
  for (int ni = 0; ni < 4; ++ni) {
    const int d = dbase + ni * 16 + (lane & 15);
    const float bias = b2[e * D_DIM + d];
#pragma unroll
    for (int mi = 0; mi < 4; ++mi) {
#pragma unroll
      for (int j = 0; j < 4; ++j) {
        const int cl = wm * 64 + mi * 16 + (lane >> 4) * 4 + j;
        const float val = (acc[mi][ni][j] + bias) * w_s[cl];
        atomicAdd(out + (size_t)tok_s[cl] * D_DIM + d, val);
      }
    }
  }
}

// ---------- launch ----------
extern "C" void kernel_launch(void* const* d_in, const int* in_sizes, int n_in,
                              void* d_out, int out_size, void* d_ws, size_t ws_size,
                              hipStream_t stream) {
  (void)in_sizes; (void)n_in; (void)out_size;
  const float* x  = (const float*)d_in[0];
  const float* cw = (const float*)d_in[1];
  const void* tidx = d_in[2];
  const float* W1 = (const float*)d_in[3];
  const float* b1 = (const float*)d_in[4];
  const float* W2 = (const float*)d_in[5];
  const float* b2 = (const float*)d_in[6];
  float* out = (float*)d_out;

  const size_t nx  = (size_t)N_DIM * D_DIM;
  const size_t nw  = (size_t)E_DIM * FF_DIM * D_DIM;
  const size_t nh  = (size_t)E_DIM * C_DIM * FF_DIM;
  const size_t nEC = (size_t)E_DIM * C_DIM;

  const size_t need = (nx + 2 * nw + nh) * 2 + nEC * 8 + 64;  // ~285 MB
  if (ws_size < need) return;

  char* p = (char*)d_ws;
  auto take = [&](size_t bytes) { char* r = p; p += bytes; return r; };
  u16* xs   = (u16*)take(nx * 2);
  u16* w1t  = (u16*)take(nw * 2);
  u16* w2t  = (u16*)take(nw * 2);
  u16* hbuf = (u16*)take(nh * 2);
  int*  tok32 = (int*)take(nEC * 4);
  float* wgp  = (float*)take(nEC * 4);
  int*  flag  = (int*)take(64);

  hipMemsetAsync(d_out, 0, nx * sizeof(float), stream);
  hipMemsetAsync(flag, 0, sizeof(int), stream);
  detect_i64_kernel<<<(int)((nEC / 2 + 255) / 256), 256, 0, stream>>>((const int*)tidx, flag);
  prep_tok_kernel<<<(int)((nEC + 255) / 256), 256, 0, stream>>>(tidx, cw, flag, tok32, wgp);
  split_x_kernel<<<(int)(nx / 8 / 256), 256, 0, stream>>>(x, xs);
  trans_split_kernel<<<dim3(FF_DIM / 64, D_DIM / 64, E_DIM), 256, 0, stream>>>(
      W1, w1t, D_DIM, FF_DIM);
  trans_split_kernel<<<dim3(D_DIM / 64, FF_DIM / 64, E_DIM), 256, 0, stream>>>(
      W2, w2t, FF_DIM, D_DIM);

  gemm1_kernel<<<(FF_DIM / 128) * (C_DIM / 128) * E_DIM, 256, 0, stream>>>(
      xs, w1t, tok32, b1, hbuf);
  gemm2_kernel<<<(D_DIM / 128) * (C_DIM / 128) * E_DIM, 256, 0, stream>>>(
      hbuf, w2t, tok32, wgp, b2, out);
}